// Round 3
// baseline (383.241 us; speedup 1.0000x reference)
//
#include <hip/hip_runtime.h>
#include <stdint.h>

#define DMODEL 1024
#define NHEADS 16
#define DKH 64
#define BATCH 2
#define SEQ 2048
#define MTOT (BATCH*SEQ)   // 4096

typedef __bf16 bf16x8 __attribute__((ext_vector_type(8)));
typedef __bf16 bf16x4 __attribute__((ext_vector_type(4)));
typedef float  f32x4  __attribute__((ext_vector_type(4)));

__device__ __forceinline__ f32x4 mfma16(bf16x8 a, bf16x8 b, f32x4 c){
  return __builtin_amdgcn_mfma_f32_16x16x32_bf16(a, b, c, 0, 0, 0);
}

// async global->LDS, 16B per lane. LDS dest must be wave-uniform base; HW lands lane i at base + i*16.
__device__ __forceinline__ void gload_lds16(const void* g, void* l){
  __builtin_amdgcn_global_load_lds(
      (const __attribute__((address_space(1))) uint32_t*)(uintptr_t)g,
      (__attribute__((address_space(3))) uint32_t*)(uint32_t)(uintptr_t)l,
      16, 0, 0);
}

__device__ __forceinline__ unsigned short f2bf(float f){
  unsigned u = __builtin_bit_cast(unsigned, f);
  u += 0x7fff + ((u >> 16) & 1);          // round-to-nearest-even
  return (unsigned short)(u >> 16);
}

// ---------------- fp32 -> bf16 convert ----------------
__global__ void cvt_kernel(const float* __restrict__ in, unsigned short* __restrict__ out, int n4){
  const float4*  in4  = (const float4*)in;
  ushort4*       out4 = (ushort4*)out;
  int i = blockIdx.x * blockDim.x + threadIdx.x;
  int stride = gridDim.x * blockDim.x;
  for (; i < n4; i += stride){
    float4 v = in4[i];
    ushort4 o;
    o.x = f2bf(v.x); o.y = f2bf(v.y); o.z = f2bf(v.z); o.w = f2bf(v.w);
    out4[i] = o;
  }
}

// ---------------- GEMM: C[m,n] = sum_k A[m,k]*B[n,k]  (B^T layout) ----------------
template<int EPI>
__global__ __launch_bounds__(256)
void gemm_bt(const __bf16* __restrict__ Ag, const __bf16* __restrict__ Bg,
             int M, int N, int K,
             __bf16* __restrict__ Qo, __bf16* __restrict__ Ko, __bf16* __restrict__ Vt,
             float* __restrict__ Co){
  __shared__ __align__(16) __bf16 As[128*32];
  __shared__ __align__(16) __bf16 Bs[128*32];
  const int tid  = threadIdx.x;
  const int wave = tid >> 6, lane = tid & 63;
  const int wr = wave >> 1, wc = wave & 1;
  const int lr = lane & 15, lg = lane >> 4;
  const int m0 = blockIdx.y * 128, n0 = blockIdx.x * 128;

  f32x4 acc[4][4] = {};

  const int srow = lane >> 2;        // 0..15
  const int scol = (lane & 3) * 8;   // 0,8,16,24
  const __bf16* gA = Ag + (size_t)(m0 + wave*32 + srow) * K + scol;
  const __bf16* gB = Bg + (size_t)(n0 + wave*32 + srow) * K + scol;
  __bf16* lA = &As[(wave*32) * 32];
  __bf16* lB = &Bs[(wave*32) * 32];

  for (int k0 = 0; k0 < K; k0 += 32){
    __syncthreads();
    gload_lds16(gA + k0,                lA);
    gload_lds16(gA + k0 + (size_t)16*K, lA + 16*32);
    gload_lds16(gB + k0,                lB);
    gload_lds16(gB + k0 + (size_t)16*K, lB + 16*32);
    __syncthreads();

    bf16x8 af[4], bfv[4];
#pragma unroll
    for (int i = 0; i < 4; i++)
      af[i] = *(const bf16x8*)&As[(wr*64 + i*16 + lr)*32 + lg*8];
#pragma unroll
    for (int j = 0; j < 4; j++)
      bfv[j] = *(const bf16x8*)&Bs[(wc*64 + j*16 + lr)*32 + lg*8];
#pragma unroll
    for (int i = 0; i < 4; i++)
#pragma unroll
      for (int j = 0; j < 4; j++)
        acc[i][j] = mfma16(af[i], bfv[j], acc[i][j]);
  }

  if (EPI == 0){
    const int three = n0 >> 10;
#pragma unroll
    for (int i = 0; i < 4; i++){
#pragma unroll
      for (int j = 0; j < 4; j++){
#pragma unroll
        for (int r = 0; r < 4; r++){
          int m = m0 + wr*64 + i*16 + lg*4 + r;
          int n = n0 + wc*64 + j*16 + lr;
          int b = m >> 11, s = m & 2047;
          int h = (n >> 6) & 15, dk = n & 63;
          __bf16 val = (__bf16)acc[i][j][r];
          if (three == 0)      Qo[(((size_t)(b*NHEADS + h))*SEQ + s)*DKH + dk] = val;
          else if (three == 1) Ko[(((size_t)(b*NHEADS + h))*SEQ + s)*DKH + dk] = val;
          else                 Vt[(((size_t)(b*NHEADS + h))*DKH + dk)*SEQ + s] = val;
        }
      }
    }
  } else {
#pragma unroll
    for (int i = 0; i < 4; i++)
#pragma unroll
      for (int j = 0; j < 4; j++)
#pragma unroll
        for (int r = 0; r < 4; r++){
          int m = m0 + wr*64 + i*16 + lg*4 + r;
          int n = n0 + wc*64 + j*16 + lr;
          Co[(size_t)m * N + n] = acc[i][j][r];
        }
  }
}

// ---------------- causal flash attention, swapped-QK^T, kv-split x4 ----------------
// Q,K: [b,h,s,dk] bf16; Vt: [b,h,dk,s] bf16; Aout: [b,s,h*64+dk] bf16
// One block per (bh, 16-row q-tile). 4 waves split the kv range into 4 balanced
// chunks; each computes partial (m, l, O) fully in registers (swapped QK^T puts a
// whole P-row in one lane; PV k-slots relabeled so P regs ARE the A-fragment).
// Partials combined once through LDS at the end.
__global__ __launch_bounds__(256)
void attn_kernel(const __bf16* __restrict__ Q, const __bf16* __restrict__ K,
                 const __bf16* __restrict__ Vt, __bf16* __restrict__ Aout){
  const int T  = 127 - blockIdx.x;               // q-tile, big tiles first
  const int bh = blockIdx.y;
  const int wave = threadIdx.x >> 6, lane = threadIdx.x & 63;
  const int lr = lane & 15, lg = lane >> 4;
  const int qw = T * 16;
  const int nkv = (T >> 2) + 1;                  // kv tiles of 64 covering [0, qw+15]
  const int kb0 = (wave * nkv) >> 2;             // this wave's chunk
  const int kb1 = ((wave + 1) * nkv) >> 2;

  const __bf16* Qh = Q  + (size_t)bh * SEQ * DKH;
  const __bf16* Kh = K  + (size_t)bh * SEQ * DKH;
  const __bf16* Vh = Vt + (size_t)bh * DKH * SEQ;

  // combine buffers (only used after the main loop)
  __shared__ float Msh[4][16];
  __shared__ float Lsh[4][16];
  __shared__ __align__(16) float Osh[4][16][68];   // stride 68: 16B-aligned rows, 2-way banks max

  bf16x8 qf0 = *(const bf16x8*)(Qh + (size_t)(qw + lr)*DKH + lg*8);
  bf16x8 qf1 = *(const bf16x8*)(Qh + (size_t)(qw + lr)*DKH + 32 + lg*8);

  f32x4 o[4] = {};
  float mrun = -1e30f, lrun = 0.f;
  const float k2 = 0.125f * 1.44269504088896340736f;   // scale * log2(e)

  // per-wave V base pointers (k-slot labeling: elem i of frag (n,ks) is
  // kv = kv0 + ks*32 + (i>>2)*16 + lg*4 + (i&3))
  const __bf16* vbase[4];
#pragma unroll
  for (int n = 0; n < 4; n++)
    vbase[n] = Vh + (size_t)(n*16 + lr)*SEQ + lg*4;

  for (int kb = kb0; kb < kb1; kb++){
    const int kv0 = kb * 64;
    // ---- QK^T (swapped): lane owns q-row = lr; sf[t][r] = S[kv0+t*16+lg*4+r][qw+lr]
    f32x4 sf[4];
#pragma unroll
    for (int t = 0; t < 4; t++){
      const __bf16* kp = Kh + (size_t)(kv0 + t*16 + lr)*DKH + lg*8;
      bf16x8 kf0 = *(const bf16x8*)kp;
      bf16x8 kf1 = *(const bf16x8*)(kp + 32);
      f32x4 c = {};
      c = mfma16(kf0, qf0, c);
      c = mfma16(kf1, qf1, c);
      sf[t] = c;
    }
    // ---- issue V loads early (consumed after the softmax chain)
    bf16x4 vlo[4][2], vhi[4][2];
#pragma unroll
    for (int n = 0; n < 4; n++)
#pragma unroll
      for (int ks = 0; ks < 2; ks++){
        const __bf16* vp = vbase[n] + kv0 + ks*32;
        vlo[n][ks] = *(const bf16x4*)(vp);
        vhi[n][ks] = *(const bf16x4*)(vp + 16);
      }
    // ---- mask + scale
    if (kv0 + 63 > qw){          // tile touches the diagonal
      const int q = qw + lr;
#pragma unroll
      for (int t = 0; t < 4; t++){
#pragma unroll
        for (int r = 0; r < 4; r++){
          int kv = kv0 + t*16 + lg*4 + r;
          sf[t][r] = (kv <= q) ? sf[t][r]*k2 : -1e30f;
        }
      }
    } else {
#pragma unroll
      for (int t = 0; t < 4; t++)
#pragma unroll
        for (int r = 0; r < 4; r++)
          sf[t][r] *= k2;
    }
    // ---- row max: in-lane over 16 values, then across the 4 lanes sharing q
    float mx = sf[0][0];
#pragma unroll
    for (int t = 0; t < 4; t++)
#pragma unroll
      for (int r = 0; r < 4; r++) mx = fmaxf(mx, sf[t][r]);
    mx = fmaxf(mx, __shfl_xor(mx, 16));
    mx = fmaxf(mx, __shfl_xor(mx, 32));

    float mn = fmaxf(mrun, mx);
    float alpha = __builtin_amdgcn_exp2f(mrun - mn);
    mrun = mn;
    lrun *= alpha;

    // ---- P = exp2(s-m), per-lane partial row sum
    float p[16];
#pragma unroll
    for (int t = 0; t < 4; t++)
#pragma unroll
      for (int r = 0; r < 4; r++){
        float v = __builtin_amdgcn_exp2f(sf[t][r] - mn);
        p[t*4 + r] = v;
        lrun += v;
      }

    // ---- rescale O (alpha of row q = lg*4+r lives at lane lg*4+r)
    float av[4];
#pragma unroll
    for (int r = 0; r < 4; r++) av[r] = __shfl(alpha, lg*4 + r);
#pragma unroll
    for (int n = 0; n < 4; n++)
#pragma unroll
      for (int r = 0; r < 4; r++) o[n][r] *= av[r];

    // ---- PV: pa regs are already the A-fragment under the relabeled k-slots
    bf16x8 pa0, pa1;
#pragma unroll
    for (int i = 0; i < 8; i++){ pa0[i] = (__bf16)p[i]; pa1[i] = (__bf16)p[8 + i]; }
#pragma unroll
    for (int n = 0; n < 4; n++){
      bf16x8 vf0 = __builtin_shufflevector(vlo[n][0], vhi[n][0], 0,1,2,3,4,5,6,7);
      bf16x8 vf1 = __builtin_shufflevector(vlo[n][1], vhi[n][1], 0,1,2,3,4,5,6,7);
      o[n] = mfma16(pa0, vf0, o[n]);
      o[n] = mfma16(pa1, vf1, o[n]);
    }
  }

  // ---- finish partial: full row-sum for this wave's chunk
  lrun += __shfl_xor(lrun, 16);
  lrun += __shfl_xor(lrun, 32);

  if (lane < 16){ Msh[wave][lr] = mrun; Lsh[wave][lr] = lrun; }
#pragma unroll
  for (int n = 0; n < 4; n++)
#pragma unroll
    for (int r = 0; r < 4; r++)
      Osh[wave][lg*4 + r][n*16 + lr] = o[n][r];
  __syncthreads();

  // ---- combine 4 partials; thread -> (q = tid>>4, dk = (tid&15)*4 .. +3)
  {
    const int q = threadIdx.x >> 4, c = threadIdx.x & 15;
    float ms = -1e30f;
#pragma unroll
    for (int w = 0; w < 4; w++) ms = fmaxf(ms, Msh[w][q]);
    float ls = 0.f;
    f32x4 acc = {};
#pragma unroll
    for (int w = 0; w < 4; w++){
      float e = __builtin_amdgcn_exp2f(Msh[w][q] - ms);
      ls += e * Lsh[w][q];
      f32x4 ov = *(const f32x4*)&Osh[w][q][c*4];
#pragma unroll
      for (int j = 0; j < 4; j++) acc[j] += e * ov[j];
    }
    float inv = 1.0f / ls;
    const int b = bh >> 4, h = bh & 15;
    bf16x4 outv;
#pragma unroll
    for (int j = 0; j < 4; j++) outv[j] = (__bf16)(acc[j] * inv);
    *(bf16x4*)(Aout + ((size_t)b*SEQ + qw + q)*DMODEL + h*DKH + c*4) = outv;
  }
}

// ---------------- launch ----------------
extern "C" void kernel_launch(void* const* d_in, const int* in_sizes, int n_in,
                              void* d_out, int out_size, void* d_ws, size_t ws_size,
                              hipStream_t stream){
  const float* x    = (const float*)d_in[0];
  const float* wqkv = (const float*)d_in[1];
  const float* wout = (const float*)d_in[2];
  float* out = (float*)d_out;
  char* ws = (char*)d_ws;

  __bf16* xb  = (__bf16*)(ws);                    //  8,388,608  x bf16 [4096,1024]
  __bf16* Ab  = (__bf16*)(ws);                    //  attn out bf16 (alias, x dead)
  __bf16* wqb = (__bf16*)(ws + 8388608);          //  6,291,456  W_qkv bf16
  __bf16* wob = (__bf16*)(ws + 14680064);         //  2,097,152  W_out bf16
  __bf16* Qb  = (__bf16*)(ws + 16777216);         //  8,388,608  Q [b,h,s,dk]
  __bf16* Kb  = (__bf16*)(ws + 25165824);         //  8,388,608  K [b,h,s,dk]
  __bf16* Vtb = (__bf16*)(ws + 33554432);         //  8,388,608  V^T [b,h,dk,s]

  cvt_kernel<<<1024, 256, 0, stream>>>(x,    (unsigned short*)xb,  (MTOT*DMODEL)/4);
  cvt_kernel<<<1024, 256, 0, stream>>>(wqkv, (unsigned short*)wqb, (3*DMODEL*DMODEL)/4);
  cvt_kernel<<<256,  256, 0, stream>>>(wout, (unsigned short*)wob, (DMODEL*DMODEL)/4);

  gemm_bt<0><<<dim3(24, 32), 256, 0, stream>>>(xb, wqb, MTOT, 3*DMODEL, DMODEL,
                                               Qb, Kb, Vtb, nullptr);
  attn_kernel<<<dim3(128, 32), 256, 0, stream>>>(Qb, Kb, Vtb, Ab);
  gemm_bt<1><<<dim3(8, 32), 256, 0, stream>>>(Ab, wob, MTOT, DMODEL, DMODEL,
                                              nullptr, nullptr, nullptr, out);
}

// Round 4
// 206.568 us; speedup vs baseline: 1.8553x; 1.8553x over previous
//
#include <hip/hip_runtime.h>
#include <stdint.h>

#define DMODEL 1024
#define NHEADS 16
#define DKH 64
#define BATCH 2
#define SEQ 2048
#define MTOT (BATCH*SEQ)   // 4096

typedef __bf16 bf16x8 __attribute__((ext_vector_type(8)));
typedef __bf16 bf16x4 __attribute__((ext_vector_type(4)));
typedef float  f32x4  __attribute__((ext_vector_type(4)));

__device__ __forceinline__ f32x4 mfma16(bf16x8 a, bf16x8 b, f32x4 c){
  return __builtin_amdgcn_mfma_f32_16x16x32_bf16(a, b, c, 0, 0, 0);
}

// async global->LDS, 16B per lane. LDS dest wave-uniform base; lane i lands at base + i*16.
__device__ __forceinline__ void gload_lds16(const void* g, void* l){
  __builtin_amdgcn_global_load_lds(
      (const __attribute__((address_space(1))) uint32_t*)(uintptr_t)g,
      (__attribute__((address_space(3))) uint32_t*)(uint32_t)(uintptr_t)l,
      16, 0, 0);
}

__device__ __forceinline__ unsigned short f2bf(float f){
  unsigned u = __builtin_bit_cast(unsigned, f);
  u += 0x7fff + ((u >> 16) & 1);          // round-to-nearest-even
  return (unsigned short)(u >> 16);
}

// ---------------- fp32 -> bf16 convert ----------------
__global__ void cvt_kernel(const float* __restrict__ in, unsigned short* __restrict__ out, int n4){
  const float4*  in4  = (const float4*)in;
  ushort4*       out4 = (ushort4*)out;
  int i = blockIdx.x * blockDim.x + threadIdx.x;
  int stride = gridDim.x * blockDim.x;
  for (; i < n4; i += stride){
    float4 v = in4[i];
    ushort4 o;
    o.x = f2bf(v.x); o.y = f2bf(v.y); o.z = f2bf(v.z); o.w = f2bf(v.w);
    out4[i] = o;
  }
}

// ---------------- GEMM: C[m,n] = sum_k A[m,k]*B[n,k]  (B^T layout) ----------------
template<int EPI>
__global__ __launch_bounds__(256)
void gemm_bt(const __bf16* __restrict__ Ag, const __bf16* __restrict__ Bg,
             int M, int N, int K,
             __bf16* __restrict__ Qo, __bf16* __restrict__ Ko, __bf16* __restrict__ Vt,
             float* __restrict__ Co){
  __shared__ __align__(16) __bf16 As[128*32];
  __shared__ __align__(16) __bf16 Bs[128*32];
  const int tid  = threadIdx.x;
  const int wave = tid >> 6, lane = tid & 63;
  const int wr = wave >> 1, wc = wave & 1;
  const int lr = lane & 15, lg = lane >> 4;
  const int m0 = blockIdx.y * 128, n0 = blockIdx.x * 128;

  f32x4 acc[4][4] = {};

  const int srow = lane >> 2;        // 0..15
  const int scol = (lane & 3) * 8;   // 0,8,16,24
  const __bf16* gA = Ag + (size_t)(m0 + wave*32 + srow) * K + scol;
  const __bf16* gB = Bg + (size_t)(n0 + wave*32 + srow) * K + scol;
  __bf16* lA = &As[(wave*32) * 32];
  __bf16* lB = &Bs[(wave*32) * 32];

  for (int k0 = 0; k0 < K; k0 += 32){
    __syncthreads();
    gload_lds16(gA + k0,                lA);
    gload_lds16(gA + k0 + (size_t)16*K, lA + 16*32);
    gload_lds16(gB + k0,                lB);
    gload_lds16(gB + k0 + (size_t)16*K, lB + 16*32);
    __syncthreads();

    bf16x8 af[4], bfv[4];
#pragma unroll
    for (int i = 0; i < 4; i++)
      af[i] = *(const bf16x8*)&As[(wr*64 + i*16 + lr)*32 + lg*8];
#pragma unroll
    for (int j = 0; j < 4; j++)
      bfv[j] = *(const bf16x8*)&Bs[(wc*64 + j*16 + lr)*32 + lg*8];
#pragma unroll
    for (int i = 0; i < 4; i++)
#pragma unroll
      for (int j = 0; j < 4; j++)
        acc[i][j] = mfma16(af[i], bfv[j], acc[i][j]);
  }

  if (EPI == 0){
    const int three = n0 >> 10;
#pragma unroll
    for (int i = 0; i < 4; i++){
#pragma unroll
      for (int j = 0; j < 4; j++){
#pragma unroll
        for (int r = 0; r < 4; r++){
          int m = m0 + wr*64 + i*16 + lg*4 + r;
          int n = n0 + wc*64 + j*16 + lr;
          int b = m >> 11, s = m & 2047;
          int h = (n >> 6) & 15, dk = n & 63;
          __bf16 val = (__bf16)acc[i][j][r];
          if (three == 0)      Qo[(((size_t)(b*NHEADS + h))*SEQ + s)*DKH + dk] = val;
          else if (three == 1) Ko[(((size_t)(b*NHEADS + h))*SEQ + s)*DKH + dk] = val;
          else                 Vt[(((size_t)(b*NHEADS + h))*DKH + dk)*SEQ + s] = val;
        }
      }
    }
  } else {
#pragma unroll
    for (int i = 0; i < 4; i++)
#pragma unroll
      for (int j = 0; j < 4; j++)
#pragma unroll
        for (int r = 0; r < 4; r++){
          int m = m0 + wr*64 + i*16 + lg*4 + r;
          int n = n0 + wc*64 + j*16 + lr;
          Co[(size_t)m * N + n] = acc[i][j][r];
        }
  }
}

// ---------------- causal flash attention, LDS-staged K/V, 8 waves/block ----------------
// Q,K: [b,h,s,dk] bf16; Vt: [b,h,dk,s] bf16; Aout: [b,s,h*64+dk] bf16
// Block j in 0..7 handles the 128-row q-tiles {j, 15-j} sequentially -> constant
// 34 kv-rounds per block; grid 8x32 = 256 blocks = 1 per CU, zero tail.
// Per kv-round: K-tile [64][128B] and V-tile [64 dk][128B] staged to LDS via
// global_load_lds (2 instrs/wave), XOR-swizzled (byte ^= (row&7)<<4) via
// pre-swizzled GLOBAL source + swizzled ds_read (both-sides involution).
// Math (swapped QK^T, P-regs-are-A-frag relabel, in-lane softmax) identical to R3.
__global__ __launch_bounds__(512)
void attn_kernel(const __bf16* __restrict__ Q, const __bf16* __restrict__ K,
                 const __bf16* __restrict__ Vt, __bf16* __restrict__ Aout){
  const int j  = blockIdx.x;                 // pair index 0..7
  const int bh = blockIdx.y;
  const int wave = threadIdx.x >> 6, lane = threadIdx.x & 63;
  const int lr = lane & 15, lg = lane >> 4;
  const int swz = (lr & 7) << 4;             // read-side XOR (row&7 == lr&7 for rows t*16+lr)

  const __bf16* Qh = Q + (size_t)bh*SEQ*DKH;
  const char* Kc = (const char*)(K  + (size_t)bh*SEQ*DKH);   // row stride 128B
  const char* Vc = (const char*)(Vt + (size_t)bh*DKH*SEQ);   // row stride 4096B

  __shared__ __align__(16) char lds[2][16384];   // [buf][ K 8KB | V 8KB ]

  // staging: wave stages rows [wave*8, wave*8+8) of each tile; lane covers
  // (row8 = lane>>3, 16B chunk cL = (lane&7)*16); global col pre-swizzled.
  const int row8 = lane >> 3;
  const int cL   = (lane & 7) << 4;
  const int cG   = cL ^ (row8 << 4);
  const int srow = wave*8 + row8;

  const int b = bh >> 4, h = bh & 15;
  const float k2 = 0.125f * 1.44269504088896340736f;   // scale * log2(e)

  for (int ph = 0; ph < 2; ph++){
    const int tb  = ph ? (15 - j) : j;       // 128-row q-tile index
    const int qw  = tb*128 + wave*16;        // wave's first q row
    const int nkv = 2*tb + 2;                // kv tiles of 64 covering q < (tb+1)*128

    bf16x8 qf0 = *(const bf16x8*)(Qh + (size_t)(qw + lr)*DKH + lg*8);
    bf16x8 qf1 = *(const bf16x8*)(Qh + (size_t)(qw + lr)*DKH + 32 + lg*8);

    f32x4 o[4] = {};
    float mrun = -1e30f, lrun = 0.f;

    // prologue: stage tile 0 into buf 0
    gload_lds16(Kc + (size_t)srow*128 + cG,  &lds[0][wave*1024]);
    gload_lds16(Vc + (size_t)srow*4096 + cG, &lds[0][8192 + wave*1024]);
    __syncthreads();

    for (int kb = 0; kb < nkv; kb++){
      const int kv0 = kb*64;
      if (kb + 1 < nkv){                     // stage next tile into other buffer
        const int nv0 = kv0 + 64;
        gload_lds16(Kc + (size_t)(nv0 + srow)*128 + cG,            &lds[(kb+1)&1][wave*1024]);
        gload_lds16(Vc + (size_t)srow*4096 + (size_t)nv0*2 + cG,   &lds[(kb+1)&1][8192 + wave*1024]);
      }
      if (kv0 <= qw + 15){                   // wave-uniform causal skip
        const char* Ks = lds[kb&1];
        const char* Vs = lds[kb&1] + 8192;

        // ---- QK^T (swapped): sf[t][r] = S[kv0+t*16+lg*4+r][qw+lr]
        f32x4 sf[4];
#pragma unroll
        for (int t = 0; t < 4; t++){
          const int row = t*16 + lr;
          bf16x8 kf0 = *(const bf16x8*)(Ks + row*128 + ((lg*16) ^ swz));
          bf16x8 kf1 = *(const bf16x8*)(Ks + row*128 + ((64 + lg*16) ^ swz));
          f32x4 c = {};
          c = mfma16(kf0, qf0, c);
          c = mfma16(kf1, qf1, c);
          sf[t] = c;
        }
        // ---- mask + scale
        if (kv0 + 63 > qw){                  // tile touches the diagonal
          const int q = qw + lr;
#pragma unroll
          for (int t = 0; t < 4; t++)
#pragma unroll
            for (int r = 0; r < 4; r++){
              int kv = kv0 + t*16 + lg*4 + r;
              sf[t][r] = (kv <= q) ? sf[t][r]*k2 : -1e30f;
            }
        } else {
#pragma unroll
          for (int t = 0; t < 4; t++)
#pragma unroll
            for (int r = 0; r < 4; r++)
              sf[t][r] *= k2;
        }
        // ---- row max: in-lane 16 values, then across 4 lanes sharing q-row lr
        float mx = sf[0][0];
#pragma unroll
        for (int t = 0; t < 4; t++)
#pragma unroll
          for (int r = 0; r < 4; r++) mx = fmaxf(mx, sf[t][r]);
        mx = fmaxf(mx, __shfl_xor(mx, 16));
        mx = fmaxf(mx, __shfl_xor(mx, 32));

        float mn = fmaxf(mrun, mx);
        float alpha = __builtin_amdgcn_exp2f(mrun - mn);
        mrun = mn;
        lrun *= alpha;

        // ---- P = exp2(s-m), per-lane partial row sum
        float p[16];
#pragma unroll
        for (int t = 0; t < 4; t++)
#pragma unroll
          for (int r = 0; r < 4; r++){
            float v = __builtin_amdgcn_exp2f(sf[t][r] - mn);
            p[t*4 + r] = v;
            lrun += v;
          }

        // ---- rescale O (alpha of q-row lg*4+r lives at lane lg*4+r)
        float av[4];
#pragma unroll
        for (int r = 0; r < 4; r++) av[r] = __shfl(alpha, lg*4 + r);
#pragma unroll
        for (int n = 0; n < 4; n++)
#pragma unroll
          for (int r = 0; r < 4; r++) o[n][r] *= av[r];

        // ---- PV: pa regs ARE the A-fragment under relabeled k-slots;
        //      V fragments from swizzled LDS (same values as R3's global loads)
        bf16x8 pa0, pa1;
#pragma unroll
        for (int i = 0; i < 8; i++){ pa0[i] = (__bf16)p[i]; pa1[i] = (__bf16)p[8 + i]; }
#pragma unroll
        for (int n = 0; n < 4; n++){
          const int row = n*16 + lr;
          bf16x4 vlo0 = *(const bf16x4*)(Vs + row*128 + ((lg*8) ^ swz));
          bf16x4 vhi0 = *(const bf16x4*)(Vs + row*128 + ((32 + lg*8) ^ swz));
          bf16x4 vlo1 = *(const bf16x4*)(Vs + row*128 + ((64 + lg*8) ^ swz));
          bf16x4 vhi1 = *(const bf16x4*)(Vs + row*128 + ((96 + lg*8) ^ swz));
          bf16x8 vf0 = __builtin_shufflevector(vlo0, vhi0, 0,1,2,3,4,5,6,7);
          bf16x8 vf1 = __builtin_shufflevector(vlo1, vhi1, 0,1,2,3,4,5,6,7);
          o[n] = mfma16(pa0, vf0, o[n]);
          o[n] = mfma16(pa1, vf1, o[n]);
        }
      }
      __syncthreads();                       // tile consumed; next staging safe
    }

    // ---- epilogue: full row sums, direct store (wave owns its 16 q-rows)
    lrun += __shfl_xor(lrun, 16);
    lrun += __shfl_xor(lrun, 32);
    float inv = 1.0f / lrun;
#pragma unroll
    for (int r = 0; r < 4; r++){
      float invr = __shfl(inv, lg*4 + r);
      __bf16* dst = Aout + ((size_t)b*SEQ + qw + lg*4 + r)*DMODEL + h*DKH;
#pragma unroll
      for (int n = 0; n < 4; n++)
        dst[n*16 + lr] = (__bf16)(o[n][r] * invr);
    }
  }
}

// ---------------- launch ----------------
extern "C" void kernel_launch(void* const* d_in, const int* in_sizes, int n_in,
                              void* d_out, int out_size, void* d_ws, size_t ws_size,
                              hipStream_t stream){
  const float* x    = (const float*)d_in[0];
  const float* wqkv = (const float*)d_in[1];
  const float* wout = (const float*)d_in[2];
  float* out = (float*)d_out;
  char* ws = (char*)d_ws;

  __bf16* xb  = (__bf16*)(ws);                    //  8,388,608  x bf16 [4096,1024]
  __bf16* Ab  = (__bf16*)(ws);                    //  attn out bf16 (alias, x dead)
  __bf16* wqb = (__bf16*)(ws + 8388608);          //  6,291,456  W_qkv bf16
  __bf16* wob = (__bf16*)(ws + 14680064);         //  2,097,152  W_out bf16
  __bf16* Qb  = (__bf16*)(ws + 16777216);         //  8,388,608  Q [b,h,s,dk]
  __bf16* Kb  = (__bf16*)(ws + 25165824);         //  8,388,608  K [b,h,s,dk]
  __bf16* Vtb = (__bf16*)(ws + 33554432);         //  8,388,608  V^T [b,h,dk,s]

  cvt_kernel<<<1024, 256, 0, stream>>>(x,    (unsigned short*)xb,  (MTOT*DMODEL)/4);
  cvt_kernel<<<1024, 256, 0, stream>>>(wqkv, (unsigned short*)wqb, (3*DMODEL*DMODEL)/4);
  cvt_kernel<<<256,  256, 0, stream>>>(wout, (unsigned short*)wob, (DMODEL*DMODEL)/4);

  gemm_bt<0><<<dim3(24, 32), 256, 0, stream>>>(xb, wqb, MTOT, 3*DMODEL, DMODEL,
                                               Qb, Kb, Vtb, nullptr);
  attn_kernel<<<dim3(8, 32), 512, 0, stream>>>(Qb, Kb, Vtb, Ab);
  gemm_bt<1><<<dim3(8, 32), 256, 0, stream>>>(Ab, wob, MTOT, DMODEL, DMODEL,
                                              nullptr, nullptr, nullptr, out);
}